// Round 15
// baseline (1533.857 us; speedup 1.0000x reference)
//
#include <hip/hip_runtime.h>
#include <math.h>

// VQ-VAE forward. inputs [16,256,64,64] f32 NCHW, codebook [1024,256] f32.
// N = 65536 points, D = 256, K = 1024.
// d_out f32: z_out [16,256,64,64] | loss | perplexity | idx [65536,1]
#define NPTS   65536
#define DDIM   256
#define KCODES 1024
#define HWSZ   4096
#define ZELEMS 16777216
#define CHW    1048576

// bf16-split GEMM, 3-product contraction 768 = [xhi|xhi|xlo].[whi|wlo|whi].
// HIGH-OCCUPANCY design v2: wave tile 64x64 (acc=64 VGPR), ~116 VGPR total,
// __launch_bounds__(512,6) -> 6 waves/SIMD = 3 blocks/CU (LDS 3x48=144 KB).
// R13 (2 blocks/CU) confirmed TLP is the overlap mechanism (+16%, MfmaUtil
// 36.8->44.5); this round scales it to 3 streams/SIMD.
// Block 512 thr = 8 waves 2Mx4N, tile 128x256. B direct global->VGPR
// (ping-pong), A via LDS (6 bufs x 8 KB, stage distance 4), gate vmcnt(5) +
// barrier every 2 steps (liveness proofs as R11).
// Loss trick: ||zq-x||^2 = best + ||x||^2 -> no x re-read in gather.
// X layout: [mt 256][chunk 16][rh 2][ms 8][lane 64][8] bf16 (64 MiB, z_out scratch)
// W layout: [ct 4][chunk 16][ch 2][ms 8][lane 64][8] bf16 (1 MiB, ws)
// ws: counts u32[1K]@0 | ww f32[1K]@4096 | partials f32[256]@8192 | Ws@16384
//     | pbest u64[4][64K]@1064960 | xxpart f32[4096]@3162112

typedef __attribute__((ext_vector_type(8))) short s16x8;
typedef __attribute__((ext_vector_type(4))) float f32x4;

#define AS1 __attribute__((address_space(1)))
#define AS3 __attribute__((address_space(3)))

__device__ __forceinline__ void bf16split(float x, unsigned short& h, unsigned short& l) {
    unsigned u  = __float_as_uint(x);
    unsigned hu = (u + 0x8000u) & 0xFFFF0000u;
    h = (unsigned short)(hu >> 16);
    float r = x - __uint_as_float(hu);
    l = (unsigned short)((__float_as_uint(r) + 0x8000u) >> 16);
}

// ------------------------------------------- conv_w: codebook -> tiles + ||w||^2
__global__ __launch_bounds__(256) void conv_w(const float* __restrict__ cb,
                                              unsigned short* __restrict__ Ws,
                                              float* __restrict__ ww) {
    int gid  = blockIdx.x * 256 + threadIdx.x;           // 0..8191
    int code = gid >> 3, o32 = gid & 7;
    int ct = code >> 8, r256 = code & 255, rh = r256 >> 7, rr = r256 & 127;
    unsigned short hi[32], lo[32];
    float ss = 0.f;
#pragma unroll
    for (int j4 = 0; j4 < 8; ++j4) {
        float4 v = *(const float4*)(cb + (size_t)code * DDIM + o32 * 32 + j4 * 4);
        ss += v.x * v.x + v.y * v.y + v.z * v.z + v.w * v.w;
        bf16split(v.x, hi[j4*4+0], lo[j4*4+0]);
        bf16split(v.y, hi[j4*4+1], lo[j4*4+1]);
        bf16split(v.z, hi[j4*4+2], lo[j4*4+2]);
        bf16split(v.w, hi[j4*4+3], lo[j4*4+3]);
    }
    ss += __shfl_down(ss, 4, 8);
    ss += __shfl_down(ss, 2, 8);
    ss += __shfl_down(ss, 1, 8);
    if (o32 == 0) ww[code] = ss;
    size_t bh = (size_t)ct * 131072 + (size_t)o32       * 8192 + rh * 4096 + (rr >> 4) * 512;
    size_t bl = (size_t)ct * 131072 + (size_t)(o32 + 8) * 8192 + rh * 4096 + (rr >> 4) * 512;
#pragma unroll
    for (int oct = 0; oct < 4; ++oct) {
        size_t fo = (size_t)((rr & 15) + 16 * oct) * 8;
        *(s16x8*)(Ws + bh + fo) = *(const s16x8*)&hi[oct * 8];
        *(s16x8*)(Ws + bl + fo) = *(const s16x8*)&lo[oct * 8];
    }
}

// ------------------- conv_x: NCHW f32 -> fragment-ordered bf16 + sum(x^2)
__global__ __launch_bounds__(256) void conv_x(const float* __restrict__ in,
                                              unsigned short* __restrict__ Xs,
                                              float* __restrict__ xxpart) {
    __shared__ float xt[32 * 128];                       // 16 KB
    __shared__ float xps[4];
    const int tid = threadIdx.x;
    const int rg = blockIdx.x >> 3, dc = blockIdx.x & 7;
    const int mt = rg >> 1, rhalf = rg & 1;
    const int b = (rg * 128) >> 12, hw0 = (rg * 128) & 4095;
    const float* src = in + (size_t)b * CHW + (size_t)(dc * 32) * HWSZ + hw0;
    float xs = 0.f;
#pragma unroll
    for (int r = 0; r < 16; ++r) {
        int e = r * 256 + tid, dd = e >> 7, i = e & 127;
        float v = src[(size_t)dd * HWSZ + i];
        xt[dd * 128 + i] = v;
        xs += v * v;
    }
#pragma unroll
    for (int o = 32; o; o >>= 1) xs += __shfl_down(xs, o, 64);
    if ((tid & 63) == 0) xps[tid >> 6] = xs;
    __syncthreads();
    if (tid == 0) xxpart[blockIdx.x] = xps[0] + xps[1] + xps[2] + xps[3];
#pragma unroll
    for (int hl = 0; hl < 2; ++hl) {
        int g = hl * 256 + tid;
        int row = g >> 2, o = g & 3;
        unsigned short hi[8], lo[8];
#pragma unroll
        for (int j = 0; j < 8; ++j)
            bf16split(xt[(o * 8 + j) * 128 + row], hi[j], lo[j]);
        size_t fo = rhalf * 4096 + (size_t)(row >> 4) * 512 + (size_t)((row & 15) + 16 * o) * 8;
        size_t bh = (size_t)mt * 131072 + (size_t)dc       * 8192 + fo;
        size_t bl = (size_t)mt * 131072 + (size_t)(dc + 8) * 8192 + fo;
        *(s16x8*)(Xs + bh) = *(const s16x8*)hi;
        *(s16x8*)(Xs + bl) = *(const s16x8*)lo;
    }
}

// ------------------- gemm_argmin: 6-waves/SIMD B-direct MFMA + argmin
// 2048 blocks (512 mbi x 4 nt) x 512 threads (8 waves 2Mx4N; wave tile 64x64).
// 24 k-steps of BK=32. XCD swizzle keeps the 4 nt of each mbi on one XCD.
__global__ __launch_bounds__(512, 6) void gemm_argmin(
        const unsigned short* __restrict__ Xs, const unsigned short* __restrict__ Ws,
        const float* __restrict__ ww, unsigned long long* __restrict__ pbest) {
    __shared__ unsigned short lds[24576];                // 48 KB = 6 bufs x 4096 shorts
    const int tid = threadIdx.x, lane = tid & 63, w = tid >> 6;
    const int wm = w >> 2, wn = w & 3;
    const int col = lane & 15, q = lane >> 4;
    const int bid = blockIdx.x;
    const int xcd = bid & 7, slot = bid >> 3;
    const int nt = slot & 3, mbi = (slot >> 2) * 8 + xcd;         // 0..511
    const int mt = mbi >> 1, rh = mbi & 1;

    const unsigned short* XsB = Xs + (size_t)mt * 131072 + rh * 4096;
    const unsigned short* Bw  = Ws + (size_t)nt * 131072
                              + (wn >> 1) * 4096 + (wn & 1) * 2048 + lane * 8;

    f32x4 acc[4][4] = {};
    s16x8 B0[4], B1[4];
    const int aoff = wm * 2048 + lane * 8;               // wm*4 subtiles of 512

    auto SA = [&](int g, int p) {                        // stage A(g): 8 KB, 1 op/thread
        const int kA = (g & 7) | ((g >> 4) << 3);        // xhi,xhi,xlo
        __builtin_amdgcn_global_load_lds(
            (const AS1 unsigned*)(XsB + kA * 8192 + tid * 8),
            (AS3 unsigned*)&lds[p * 4096 + (tid >> 6) * 512 + (tid & 63) * 8], 16, 0, 0);
    };
    auto LB = [&](int g, s16x8* B) {                     // B(g) global->regs: 4 dwordx4
        const int kW = (g & 7) | (((g >> 3) & 1) << 3);  // whi,wlo,whi
        const s16x8* src = (const s16x8*)(Bw + kW * 8192);
        B[0] = src[0]; B[1] = src[64]; B[2] = src[128]; B[3] = src[192];
    };
#define BAR do { __builtin_amdgcn_s_barrier(); __builtin_amdgcn_sched_barrier(0); } while (0)

    // step: 4 A ds_reads | LB(g+1)->Bn | SA(g+4) | 16 MFMA | [gate+bar if odd]
    auto TILE = [&](int g, int p, int pstg, const s16x8* Bc, s16x8* Bn, bool sync) {
        s16x8 a[4];
#pragma unroll
        for (int mf = 0; mf < 4; ++mf)
            a[mf] = *(const s16x8*)&lds[p * 4096 + aoff + mf * 512];
        if (g + 1 < 24) LB(g + 1, Bn);
        if (g + 4 < 24) SA(g + 4, pstg);
        __builtin_amdgcn_s_setprio(1);
#pragma unroll
        for (int mf = 0; mf < 4; ++mf) {
            acc[mf][0] = __builtin_amdgcn_mfma_f32_16x16x32_bf16(a[mf], Bc[0], acc[mf][0], 0, 0, 0);
            acc[mf][1] = __builtin_amdgcn_mfma_f32_16x16x32_bf16(a[mf], Bc[1], acc[mf][1], 0, 0, 0);
            acc[mf][2] = __builtin_amdgcn_mfma_f32_16x16x32_bf16(a[mf], Bc[2], acc[mf][2], 0, 0, 0);
            acc[mf][3] = __builtin_amdgcn_mfma_f32_16x16x32_bf16(a[mf], Bc[3], acc[mf][3], 0, 0, 0);
        }
        __builtin_amdgcn_s_setprio(0);
        if (sync) {
            asm volatile("s_waitcnt vmcnt(5)" ::: "memory");
            BAR;
        }
    };

    // prologue: stage A(0..3) -> bufs 0..3; B(0) -> regs; drain stages; barrier
    SA(0, 0); SA(1, 1); SA(2, 2); SA(3, 3);
    LB(0, B0);
    asm volatile("s_waitcnt vmcnt(4)" ::: "memory");
    BAR;

    for (int t6 = 0; t6 < 3; ++t6) {                     // t = 0..17
        TILE(t6 * 6 + 0, 0, 4, B0, B1, false);
        TILE(t6 * 6 + 1, 1, 5, B1, B0, true);
        TILE(t6 * 6 + 2, 2, 0, B0, B1, false);
        TILE(t6 * 6 + 3, 3, 1, B1, B0, true);
        TILE(t6 * 6 + 4, 4, 2, B0, B1, false);
        TILE(t6 * 6 + 5, 5, 3, B1, B0, true);
    }
    TILE(18, 0, 4, B0, B1, false);
    TILE(19, 1, 5, B1, B0, true);
    TILE(20, 2, 0, B0, B1, false);
    TILE(21, 3, 1, B1, B0, true);
    TILE(22, 4, 2, B0, B1, false);
    TILE(23, 5, 3, B1, B0, false);

    // ---- epilogue: per-row argmin; 2-step butterfly + [128][17] LDS fold
    __syncthreads();
    unsigned long long* kbuf = (unsigned long long*)lds;  // [128][17] u64 = 17.4 KB
    float wv[4];
#pragma unroll
    for (int nf = 0; nf < 4; ++nf) wv[nf] = ww[nt * 256 + wn * 64 + nf * 16 + col];
#pragma unroll
    for (int mf = 0; mf < 4; ++mf)
#pragma unroll
        for (int r = 0; r < 4; ++r) {
            unsigned long long key = ~0ull;
#pragma unroll
            for (int nf = 0; nf < 4; ++nf) {
                int kg = nt * 256 + wn * 64 + nf * 16 + col;
                float sd = wv[nf] - 2.f * acc[mf][nf][r];
                unsigned u = __float_as_uint(sd);
                u = (u & 0x80000000u) ? ~u : (u | 0x80000000u);
                unsigned long long kk = ((unsigned long long)u << 32) | (unsigned)kg;
                key = kk < key ? kk : key;
            }
#pragma unroll
            for (int off = 1; off < 4; off <<= 1) {
                unsigned klo = __shfl_xor((unsigned)key, off, 64);
                unsigned khi = __shfl_xor((unsigned)(key >> 32), off, 64);
                unsigned long long ok = ((unsigned long long)khi << 32) | klo;
                key = ok < key ? ok : key;
            }
            if ((col & 3) == 0)
                kbuf[(wm * 64 + mf * 16 + q * 4 + r) * 17 + wn * 4 + (col >> 2)] = key;
        }
    __syncthreads();
    if (tid < 128) {
        const unsigned long long* rowp = kbuf + tid * 17;
        unsigned long long km = rowp[0];
#pragma unroll
        for (int i = 1; i < 16; ++i) {
            unsigned long long k = rowp[i];
            km = k < km ? k : km;
        }
        pbest[(size_t)nt * 65536 + mbi * 128 + tid] = km;
    }
#undef BAR
}

// ---------- gather: cross-block argmin + idx + z_out + sum(best) + counts
__global__ __launch_bounds__(256) void gather_kernel(
        const float* __restrict__ cb, const unsigned long long* __restrict__ pbest,
        float* __restrict__ idx_out, unsigned int* __restrict__ counts,
        float* __restrict__ zout, float* __restrict__ partials) {
    const int tid = threadIdx.x;
    const int n   = blockIdx.x * 256 + tid;
    unsigned long long km = pbest[n];
#pragma unroll
    for (int nt = 1; nt < 4; ++nt) {
        unsigned long long k = pbest[(size_t)nt * 65536 + n];
        km = k < km ? k : km;
    }
    const int r = (int)(km & 0xFFFFFFFFu);
    idx_out[n] = (float)r;
    atomicAdd(&counts[r], 1u);

    // decode best = ww[r] - 2 x.w_r  (monotonic-u32 inverse)
    unsigned m = (unsigned)(km >> 32);
    m = (m & 0x80000000u) ? (m & 0x7FFFFFFFu) : ~m;
    float sd = __uint_as_float(m);

    const int b = n >> 12, hw = n & 4095;
    const float4* row4 = (const float4*)(cb + (size_t)r * DDIM);
    float* zp = zout + (size_t)b * CHW + hw;
#pragma unroll 8
    for (int c4 = 0; c4 < 64; ++c4) {
        float4 v = row4[c4];
        zp[(size_t)(c4 * 4 + 0) * HWSZ] = v.x;
        zp[(size_t)(c4 * 4 + 1) * HWSZ] = v.y;
        zp[(size_t)(c4 * 4 + 2) * HWSZ] = v.z;
        zp[(size_t)(c4 * 4 + 3) * HWSZ] = v.w;
    }
#pragma unroll
    for (int o = 32; o; o >>= 1) sd += __shfl_down(sd, o, 64);
    __shared__ float ps[4];
    if ((tid & 63) == 0) ps[tid >> 6] = sd;
    __syncthreads();
    if (tid == 0) partials[blockIdx.x] = ps[0] + ps[1] + ps[2] + ps[3];
}

// ------------------------------------------------------- loss + perplexity
__global__ __launch_bounds__(256) void final_kernel(
        const float* __restrict__ partials, const float* __restrict__ xxpart,
        const unsigned int* __restrict__ counts,
        float* __restrict__ out_loss, float* __restrict__ out_perp) {
    const int tid = threadIdx.x;
    float s = partials[tid];                             // sum(best) partials
#pragma unroll
    for (int i = 0; i < 16; ++i) s += xxpart[tid * 16 + i];  // + sum(x^2)
    float e = 0.f;
#pragma unroll
    for (int qq = 0; qq < 4; ++qq) {
        float p = (float)counts[tid * 4 + qq] * (1.f / 65536.f);
        e += p * logf(p + 1e-10f);
    }
#pragma unroll
    for (int o = 32; o; o >>= 1) {
        s += __shfl_down(s, o, 64);
        e += __shfl_down(e, o, 64);
    }
    __shared__ float ss[4], es[4];
    if ((tid & 63) == 0) { ss[tid >> 6] = s; es[tid >> 6] = e; }
    __syncthreads();
    if (tid == 0) {
        float S = ss[0] + ss[1] + ss[2] + ss[3];
        float E = es[0] + es[1] + es[2] + es[3];
        *out_loss = 0.25f * (S / (float)ZELEMS);
        *out_perp = expf(-E);
    }
}

extern "C" void kernel_launch(void* const* d_in, const int* in_sizes, int n_in,
                              void* d_out, int out_size, void* d_ws, size_t ws_size,
                              hipStream_t stream) {
    (void)in_sizes; (void)n_in; (void)out_size; (void)ws_size;
    const float* in = (const float*)d_in[0];
    const float* cb = (const float*)d_in[1];
    float* out  = (float*)d_out;
    float* zout = out;
    float* loss = out + ZELEMS;
    float* perp = out + ZELEMS + 1;
    float* idxf = out + ZELEMS + 2;

    unsigned int*       counts   = (unsigned int*)d_ws;
    float*              ww       = (float*)((char*)d_ws + 4096);
    float*              partials = (float*)((char*)d_ws + 8192);
    unsigned short*     Ws       = (unsigned short*)((char*)d_ws + 16384);
    unsigned long long* pbest    = (unsigned long long*)((char*)d_ws + 1064960);
    float*              xxpart   = (float*)((char*)d_ws + 3162112);
    unsigned short*     Xs       = (unsigned short*)zout;  // scratch; overwritten later

    hipMemsetAsync(counts, 0, 4096, stream);
    conv_w      <<<32,   256, 0, stream>>>(cb, Ws, ww);
    conv_x      <<<4096, 256, 0, stream>>>(in, Xs, xxpart);
    gemm_argmin <<<2048, 512, 0, stream>>>(Xs, Ws, ww, pbest);
    gather_kernel<<<256, 256, 0, stream>>>(cb, pbest, idxf, counts, zout, partials);
    final_kernel <<<1,   256, 0, stream>>>(partials, xxpart, counts, loss, perp);
}

// Round 16
// 179.167 us; speedup vs baseline: 8.5611x; 8.5611x over previous
//
#include <hip/hip_runtime.h>
#include <math.h>

// VQ-VAE forward. inputs [16,256,64,64] f32 NCHW, codebook [1024,256] f32.
// N = 65536 points, D = 256, K = 1024.
// d_out f32: z_out [16,256,64,64] | loss | perplexity | idx [65536,1]
#define NPTS   65536
#define DDIM   256
#define KCODES 1024
#define HWSZ   4096
#define ZELEMS 16777216
#define CHW    1048576

// bf16-split GEMM, 3-product contraction 768 = [xhi|xhi|xlo].[whi|wlo|whi].
// HIGH-OCCUPANCY design (R13 config, reverted from the R14 spill): wave tile
// 64x64 (acc=64 VGPR), ~116 VGPR live -> __launch_bounds__(512,4) = 4
// waves/SIMD (2 blocks/CU) -- the measured occupancy ceiling for this acc
// size (6 waves/SIMD caps waves at ~85 regs -> catastrophic spill, R14).
// R13 confirmed TLP is the pipe-overlap mechanism (+16%, MfmaUtil 36.8->44.5).
// This round: drop setprio (m190: null-to-neg on non-phase-split GEMM) and
// fully unroll the K-loop (literal addresses, less VALU/SALU).
// Block 512 thr = 8 waves 2Mx4N, tile 128x256. B direct global->VGPR
// (ping-pong), A via LDS (6 bufs x 8 KB, stage distance 4), gate vmcnt(5) +
// barrier every 2 steps (liveness proofs as R11).
// Loss trick: ||zq-x||^2 = best + ||x||^2 -> no x re-read in gather.
// X layout: [mt 256][chunk 16][rh 2][ms 8][lane 64][8] bf16 (64 MiB, z_out scratch)
// W layout: [ct 4][chunk 16][ch 2][ms 8][lane 64][8] bf16 (1 MiB, ws)
// ws: counts u32[1K]@0 | ww f32[1K]@4096 | partials f32[256]@8192 | Ws@16384
//     | pbest u64[4][64K]@1064960 | xxpart f32[4096]@3162112

typedef __attribute__((ext_vector_type(8))) short s16x8;
typedef __attribute__((ext_vector_type(4))) float f32x4;

#define AS1 __attribute__((address_space(1)))
#define AS3 __attribute__((address_space(3)))

__device__ __forceinline__ void bf16split(float x, unsigned short& h, unsigned short& l) {
    unsigned u  = __float_as_uint(x);
    unsigned hu = (u + 0x8000u) & 0xFFFF0000u;
    h = (unsigned short)(hu >> 16);
    float r = x - __uint_as_float(hu);
    l = (unsigned short)((__float_as_uint(r) + 0x8000u) >> 16);
}

// ------------------------------------------- conv_w: codebook -> tiles + ||w||^2
__global__ __launch_bounds__(256) void conv_w(const float* __restrict__ cb,
                                              unsigned short* __restrict__ Ws,
                                              float* __restrict__ ww) {
    int gid  = blockIdx.x * 256 + threadIdx.x;           // 0..8191
    int code = gid >> 3, o32 = gid & 7;
    int ct = code >> 8, r256 = code & 255, rh = r256 >> 7, rr = r256 & 127;
    unsigned short hi[32], lo[32];
    float ss = 0.f;
#pragma unroll
    for (int j4 = 0; j4 < 8; ++j4) {
        float4 v = *(const float4*)(cb + (size_t)code * DDIM + o32 * 32 + j4 * 4);
        ss += v.x * v.x + v.y * v.y + v.z * v.z + v.w * v.w;
        bf16split(v.x, hi[j4*4+0], lo[j4*4+0]);
        bf16split(v.y, hi[j4*4+1], lo[j4*4+1]);
        bf16split(v.z, hi[j4*4+2], lo[j4*4+2]);
        bf16split(v.w, hi[j4*4+3], lo[j4*4+3]);
    }
    ss += __shfl_down(ss, 4, 8);
    ss += __shfl_down(ss, 2, 8);
    ss += __shfl_down(ss, 1, 8);
    if (o32 == 0) ww[code] = ss;
    size_t bh = (size_t)ct * 131072 + (size_t)o32       * 8192 + rh * 4096 + (rr >> 4) * 512;
    size_t bl = (size_t)ct * 131072 + (size_t)(o32 + 8) * 8192 + rh * 4096 + (rr >> 4) * 512;
#pragma unroll
    for (int oct = 0; oct < 4; ++oct) {
        size_t fo = (size_t)((rr & 15) + 16 * oct) * 8;
        *(s16x8*)(Ws + bh + fo) = *(const s16x8*)&hi[oct * 8];
        *(s16x8*)(Ws + bl + fo) = *(const s16x8*)&lo[oct * 8];
    }
}

// ------------------- conv_x: NCHW f32 -> fragment-ordered bf16 + sum(x^2)
__global__ __launch_bounds__(256) void conv_x(const float* __restrict__ in,
                                              unsigned short* __restrict__ Xs,
                                              float* __restrict__ xxpart) {
    __shared__ float xt[32 * 128];                       // 16 KB
    __shared__ float xps[4];
    const int tid = threadIdx.x;
    const int rg = blockIdx.x >> 3, dc = blockIdx.x & 7;
    const int mt = rg >> 1, rhalf = rg & 1;
    const int b = (rg * 128) >> 12, hw0 = (rg * 128) & 4095;
    const float* src = in + (size_t)b * CHW + (size_t)(dc * 32) * HWSZ + hw0;
    float xs = 0.f;
#pragma unroll
    for (int r = 0; r < 16; ++r) {
        int e = r * 256 + tid, dd = e >> 7, i = e & 127;
        float v = src[(size_t)dd * HWSZ + i];
        xt[dd * 128 + i] = v;
        xs += v * v;
    }
#pragma unroll
    for (int o = 32; o; o >>= 1) xs += __shfl_down(xs, o, 64);
    if ((tid & 63) == 0) xps[tid >> 6] = xs;
    __syncthreads();
    if (tid == 0) xxpart[blockIdx.x] = xps[0] + xps[1] + xps[2] + xps[3];
#pragma unroll
    for (int hl = 0; hl < 2; ++hl) {
        int g = hl * 256 + tid;
        int row = g >> 2, o = g & 3;
        unsigned short hi[8], lo[8];
#pragma unroll
        for (int j = 0; j < 8; ++j)
            bf16split(xt[(o * 8 + j) * 128 + row], hi[j], lo[j]);
        size_t fo = rhalf * 4096 + (size_t)(row >> 4) * 512 + (size_t)((row & 15) + 16 * o) * 8;
        size_t bh = (size_t)mt * 131072 + (size_t)dc       * 8192 + fo;
        size_t bl = (size_t)mt * 131072 + (size_t)(dc + 8) * 8192 + fo;
        *(s16x8*)(Xs + bh) = *(const s16x8*)hi;
        *(s16x8*)(Xs + bl) = *(const s16x8*)lo;
    }
}

// ------------------- gemm_argmin: 4-waves/SIMD B-direct MFMA + argmin
// 2048 blocks (512 mbi x 4 nt) x 512 threads (8 waves 2Mx4N; wave tile 64x64).
// 24 k-steps of BK=32. XCD swizzle keeps the 4 nt of each mbi on one XCD.
__global__ __launch_bounds__(512, 4) void gemm_argmin(
        const unsigned short* __restrict__ Xs, const unsigned short* __restrict__ Ws,
        const float* __restrict__ ww, unsigned long long* __restrict__ pbest) {
    __shared__ unsigned short lds[24576];                // 48 KB = 6 bufs x 4096 shorts
    const int tid = threadIdx.x, lane = tid & 63, w = tid >> 6;
    const int wm = w >> 2, wn = w & 3;
    const int col = lane & 15, q = lane >> 4;
    const int bid = blockIdx.x;
    const int xcd = bid & 7, slot = bid >> 3;
    const int nt = slot & 3, mbi = (slot >> 2) * 8 + xcd;         // 0..511
    const int mt = mbi >> 1, rh = mbi & 1;

    const unsigned short* XsB = Xs + (size_t)mt * 131072 + rh * 4096;
    const unsigned short* Bw  = Ws + (size_t)nt * 131072
                              + (wn >> 1) * 4096 + (wn & 1) * 2048 + lane * 8;

    f32x4 acc[4][4] = {};
    s16x8 B0[4], B1[4];
    const int aoff = wm * 2048 + lane * 8;               // wm*4 subtiles of 512

    auto SA = [&](int g, int p) {                        // stage A(g): 8 KB, 1 op/thread
        const int kA = (g & 7) | ((g >> 4) << 3);        // xhi,xhi,xlo
        __builtin_amdgcn_global_load_lds(
            (const AS1 unsigned*)(XsB + kA * 8192 + tid * 8),
            (AS3 unsigned*)&lds[p * 4096 + (tid >> 6) * 512 + (tid & 63) * 8], 16, 0, 0);
    };
    auto LB = [&](int g, s16x8* B) {                     // B(g) global->regs: 4 dwordx4
        const int kW = (g & 7) | (((g >> 3) & 1) << 3);  // whi,wlo,whi
        const s16x8* src = (const s16x8*)(Bw + kW * 8192);
        B[0] = src[0]; B[1] = src[64]; B[2] = src[128]; B[3] = src[192];
    };
#define BAR do { __builtin_amdgcn_s_barrier(); __builtin_amdgcn_sched_barrier(0); } while (0)

    // step: 4 A ds_reads | LB(g+1)->Bn | SA(g+4) | 16 MFMA | [gate+bar if odd]
    auto TILE = [&](int g, int p, int pstg, const s16x8* Bc, s16x8* Bn, bool sync) {
        s16x8 a[4];
#pragma unroll
        for (int mf = 0; mf < 4; ++mf)
            a[mf] = *(const s16x8*)&lds[p * 4096 + aoff + mf * 512];
        if (g + 1 < 24) LB(g + 1, Bn);
        if (g + 4 < 24) SA(g + 4, pstg);
#pragma unroll
        for (int mf = 0; mf < 4; ++mf) {
            acc[mf][0] = __builtin_amdgcn_mfma_f32_16x16x32_bf16(a[mf], Bc[0], acc[mf][0], 0, 0, 0);
            acc[mf][1] = __builtin_amdgcn_mfma_f32_16x16x32_bf16(a[mf], Bc[1], acc[mf][1], 0, 0, 0);
            acc[mf][2] = __builtin_amdgcn_mfma_f32_16x16x32_bf16(a[mf], Bc[2], acc[mf][2], 0, 0, 0);
            acc[mf][3] = __builtin_amdgcn_mfma_f32_16x16x32_bf16(a[mf], Bc[3], acc[mf][3], 0, 0, 0);
        }
        if (sync) {
            asm volatile("s_waitcnt vmcnt(5)" ::: "memory");
            BAR;
        }
    };

    // prologue: stage A(0..3) -> bufs 0..3; B(0) -> regs; drain stages; barrier
    SA(0, 0); SA(1, 1); SA(2, 2); SA(3, 3);
    LB(0, B0);
    asm volatile("s_waitcnt vmcnt(4)" ::: "memory");
    BAR;

#pragma unroll
    for (int t6 = 0; t6 < 3; ++t6) {                     // t = 0..17, fully unrolled
        TILE(t6 * 6 + 0, 0, 4, B0, B1, false);
        TILE(t6 * 6 + 1, 1, 5, B1, B0, true);
        TILE(t6 * 6 + 2, 2, 0, B0, B1, false);
        TILE(t6 * 6 + 3, 3, 1, B1, B0, true);
        TILE(t6 * 6 + 4, 4, 2, B0, B1, false);
        TILE(t6 * 6 + 5, 5, 3, B1, B0, true);
    }
    TILE(18, 0, 4, B0, B1, false);
    TILE(19, 1, 5, B1, B0, true);
    TILE(20, 2, 0, B0, B1, false);
    TILE(21, 3, 1, B1, B0, true);
    TILE(22, 4, 2, B0, B1, false);
    TILE(23, 5, 3, B1, B0, false);

    // ---- epilogue: per-row argmin; 2-step butterfly + [128][17] LDS fold
    __syncthreads();
    unsigned long long* kbuf = (unsigned long long*)lds;  // [128][17] u64 = 17.4 KB
    float wv[4];
#pragma unroll
    for (int nf = 0; nf < 4; ++nf) wv[nf] = ww[nt * 256 + wn * 64 + nf * 16 + col];
#pragma unroll
    for (int mf = 0; mf < 4; ++mf)
#pragma unroll
        for (int r = 0; r < 4; ++r) {
            unsigned long long key = ~0ull;
#pragma unroll
            for (int nf = 0; nf < 4; ++nf) {
                int kg = nt * 256 + wn * 64 + nf * 16 + col;
                float sd = wv[nf] - 2.f * acc[mf][nf][r];
                unsigned u = __float_as_uint(sd);
                u = (u & 0x80000000u) ? ~u : (u | 0x80000000u);
                unsigned long long kk = ((unsigned long long)u << 32) | (unsigned)kg;
                key = kk < key ? kk : key;
            }
#pragma unroll
            for (int off = 1; off < 4; off <<= 1) {
                unsigned klo = __shfl_xor((unsigned)key, off, 64);
                unsigned khi = __shfl_xor((unsigned)(key >> 32), off, 64);
                unsigned long long ok = ((unsigned long long)khi << 32) | klo;
                key = ok < key ? ok : key;
            }
            if ((col & 3) == 0)
                kbuf[(wm * 64 + mf * 16 + q * 4 + r) * 17 + wn * 4 + (col >> 2)] = key;
        }
    __syncthreads();
    if (tid < 128) {
        const unsigned long long* rowp = kbuf + tid * 17;
        unsigned long long km = rowp[0];
#pragma unroll
        for (int i = 1; i < 16; ++i) {
            unsigned long long k = rowp[i];
            km = k < km ? k : km;
        }
        pbest[(size_t)nt * 65536 + mbi * 128 + tid] = km;
    }
#undef BAR
}

// ---------- gather: cross-block argmin + idx + z_out + sum(best) + counts
__global__ __launch_bounds__(256) void gather_kernel(
        const float* __restrict__ cb, const unsigned long long* __restrict__ pbest,
        float* __restrict__ idx_out, unsigned int* __restrict__ counts,
        float* __restrict__ zout, float* __restrict__ partials) {
    const int tid = threadIdx.x;
    const int n   = blockIdx.x * 256 + tid;
    unsigned long long km = pbest[n];
#pragma unroll
    for (int nt = 1; nt < 4; ++nt) {
        unsigned long long k = pbest[(size_t)nt * 65536 + n];
        km = k < km ? k : km;
    }
    const int r = (int)(km & 0xFFFFFFFFu);
    idx_out[n] = (float)r;
    atomicAdd(&counts[r], 1u);

    // decode best = ww[r] - 2 x.w_r  (monotonic-u32 inverse)
    unsigned m = (unsigned)(km >> 32);
    m = (m & 0x80000000u) ? (m & 0x7FFFFFFFu) : ~m;
    float sd = __uint_as_float(m);

    const int b = n >> 12, hw = n & 4095;
    const float4* row4 = (const float4*)(cb + (size_t)r * DDIM);
    float* zp = zout + (size_t)b * CHW + hw;
#pragma unroll 8
    for (int c4 = 0; c4 < 64; ++c4) {
        float4 v = row4[c4];
        zp[(size_t)(c4 * 4 + 0) * HWSZ] = v.x;
        zp[(size_t)(c4 * 4 + 1) * HWSZ] = v.y;
        zp[(size_t)(c4 * 4 + 2) * HWSZ] = v.z;
        zp[(size_t)(c4 * 4 + 3) * HWSZ] = v.w;
    }
#pragma unroll
    for (int o = 32; o; o >>= 1) sd += __shfl_down(sd, o, 64);
    __shared__ float ps[4];
    if ((tid & 63) == 0) ps[tid >> 6] = sd;
    __syncthreads();
    if (tid == 0) partials[blockIdx.x] = ps[0] + ps[1] + ps[2] + ps[3];
}

// ------------------------------------------------------- loss + perplexity
__global__ __launch_bounds__(256) void final_kernel(
        const float* __restrict__ partials, const float* __restrict__ xxpart,
        const unsigned int* __restrict__ counts,
        float* __restrict__ out_loss, float* __restrict__ out_perp) {
    const int tid = threadIdx.x;
    float s = partials[tid];                             // sum(best) partials
#pragma unroll
    for (int i = 0; i < 16; ++i) s += xxpart[tid * 16 + i];  // + sum(x^2)
    float e = 0.f;
#pragma unroll
    for (int qq = 0; qq < 4; ++qq) {
        float p = (float)counts[tid * 4 + qq] * (1.f / 65536.f);
        e += p * logf(p + 1e-10f);
    }
#pragma unroll
    for (int o = 32; o; o >>= 1) {
        s += __shfl_down(s, o, 64);
        e += __shfl_down(e, o, 64);
    }
    __shared__ float ss[4], es[4];
    if ((tid & 63) == 0) { ss[tid >> 6] = s; es[tid >> 6] = e; }
    __syncthreads();
    if (tid == 0) {
        float S = ss[0] + ss[1] + ss[2] + ss[3];
        float E = es[0] + es[1] + es[2] + es[3];
        *out_loss = 0.25f * (S / (float)ZELEMS);
        *out_perp = expf(-E);
    }
}

extern "C" void kernel_launch(void* const* d_in, const int* in_sizes, int n_in,
                              void* d_out, int out_size, void* d_ws, size_t ws_size,
                              hipStream_t stream) {
    (void)in_sizes; (void)n_in; (void)out_size; (void)ws_size;
    const float* in = (const float*)d_in[0];
    const float* cb = (const float*)d_in[1];
    float* out  = (float*)d_out;
    float* zout = out;
    float* loss = out + ZELEMS;
    float* perp = out + ZELEMS + 1;
    float* idxf = out + ZELEMS + 2;

    unsigned int*       counts   = (unsigned int*)d_ws;
    float*              ww       = (float*)((char*)d_ws + 4096);
    float*              partials = (float*)((char*)d_ws + 8192);
    unsigned short*     Ws       = (unsigned short*)((char*)d_ws + 16384);
    unsigned long long* pbest    = (unsigned long long*)((char*)d_ws + 1064960);
    float*              xxpart   = (float*)((char*)d_ws + 3162112);
    unsigned short*     Xs       = (unsigned short*)zout;  // scratch; overwritten later

    hipMemsetAsync(counts, 0, 4096, stream);
    conv_w      <<<32,   256, 0, stream>>>(cb, Ws, ww);
    conv_x      <<<4096, 256, 0, stream>>>(in, Xs, xxpart);
    gemm_argmin <<<2048, 512, 0, stream>>>(Xs, Ws, ww, pbest);
    gather_kernel<<<256, 256, 0, stream>>>(cb, pbest, idxf, counts, zout, partials);
    final_kernel <<<1,   256, 0, stream>>>(partials, xxpart, counts, loss, perp);
}

// Round 17
// 169.478 us; speedup vs baseline: 9.0505x; 1.0572x over previous
//
#include <hip/hip_runtime.h>
#include <math.h>

// VQ-VAE forward. inputs [16,256,64,64] f32 NCHW, codebook [1024,256] f32.
// N = 65536 points, D = 256, K = 1024.
// d_out f32: z_out [16,256,64,64] | loss | perplexity | idx [65536,1]
#define NPTS   65536
#define DDIM   256
#define KCODES 1024
#define HWSZ   4096
#define ZELEMS 16777216
#define CHW    1048576

// bf16-split GEMM, 3-product contraction 768 = [xhi|xhi|xlo].[whi|wlo|whi].
// R15 gemm kept verbatim (measured best: 101.7 us, 4 waves/SIMD ceiling).
// This round: fuse {memset, conv_w, conv_x} into one prep dispatch (grid
// 4128: blocks 0..31 = conv_w + counts-zero, 32.. = conv_x) and vectorize
// conv_x global reads to float4 (G13).
// Loss trick: ||zq-x||^2 = best + ||x||^2 -> no x re-read in gather.
// X layout: [mt 256][chunk 16][rh 2][ms 8][lane 64][8] bf16 (64 MiB, z_out scratch)
// W layout: [ct 4][chunk 16][ch 2][ms 8][lane 64][8] bf16 (1 MiB, ws)
// ws: counts u32[1K]@0 | ww f32[1K]@4096 | partials f32[256]@8192 | Ws@16384
//     | pbest u64[4][64K]@1064960 | xxpart f32[4096]@3162112

typedef __attribute__((ext_vector_type(8))) short s16x8;
typedef __attribute__((ext_vector_type(4))) float f32x4;

#define AS1 __attribute__((address_space(1)))
#define AS3 __attribute__((address_space(3)))

__device__ __forceinline__ void bf16split(float x, unsigned short& h, unsigned short& l) {
    unsigned u  = __float_as_uint(x);
    unsigned hu = (u + 0x8000u) & 0xFFFF0000u;
    h = (unsigned short)(hu >> 16);
    float r = x - __uint_as_float(hu);
    l = (unsigned short)((__float_as_uint(r) + 0x8000u) >> 16);
}

// -------- prep: blocks 0..31 conv_w (+ counts zero), blocks 32..4127 conv_x
__global__ __launch_bounds__(256) void prep_kernel(
        const float* __restrict__ cb, const float* __restrict__ in,
        unsigned short* __restrict__ Ws, float* __restrict__ ww,
        unsigned short* __restrict__ Xs, float* __restrict__ xxpart,
        unsigned int* __restrict__ counts) {
    const int tid = threadIdx.x;
    if (blockIdx.x < 32) {
        // ---- conv_w path + zero counts
        int gid = blockIdx.x * 256 + tid;                // 0..8191
        if (gid < 1024) counts[gid] = 0u;
        int code = gid >> 3, o32 = gid & 7;
        int ct = code >> 8, r256 = code & 255, rh = r256 >> 7, rr = r256 & 127;
        unsigned short hi[32], lo[32];
        float ss = 0.f;
#pragma unroll
        for (int j4 = 0; j4 < 8; ++j4) {
            float4 v = *(const float4*)(cb + (size_t)code * DDIM + o32 * 32 + j4 * 4);
            ss += v.x * v.x + v.y * v.y + v.z * v.z + v.w * v.w;
            bf16split(v.x, hi[j4*4+0], lo[j4*4+0]);
            bf16split(v.y, hi[j4*4+1], lo[j4*4+1]);
            bf16split(v.z, hi[j4*4+2], lo[j4*4+2]);
            bf16split(v.w, hi[j4*4+3], lo[j4*4+3]);
        }
        ss += __shfl_down(ss, 4, 8);
        ss += __shfl_down(ss, 2, 8);
        ss += __shfl_down(ss, 1, 8);
        if (o32 == 0) ww[code] = ss;
        size_t bh = (size_t)ct * 131072 + (size_t)o32       * 8192 + rh * 4096 + (rr >> 4) * 512;
        size_t bl = (size_t)ct * 131072 + (size_t)(o32 + 8) * 8192 + rh * 4096 + (rr >> 4) * 512;
#pragma unroll
        for (int oct = 0; oct < 4; ++oct) {
            size_t fo = (size_t)((rr & 15) + 16 * oct) * 8;
            *(s16x8*)(Ws + bh + fo) = *(const s16x8*)&hi[oct * 8];
            *(s16x8*)(Ws + bl + fo) = *(const s16x8*)&lo[oct * 8];
        }
        return;
    }
    // ---- conv_x path: NCHW f32 -> fragment-ordered bf16 + sum(x^2)
    __shared__ float xt[32 * 128];                       // 16 KB
    __shared__ float xps[4];
    const int cbid = blockIdx.x - 32;                    // 0..4095
    const int rg = cbid >> 3, dc = cbid & 7;
    const int mt = rg >> 1, rhalf = rg & 1;
    const int b = (rg * 128) >> 12, hw0 = (rg * 128) & 4095;
    const float* src = in + (size_t)b * CHW + (size_t)(dc * 32) * HWSZ + hw0;
    float xs = 0.f;
#pragma unroll
    for (int r = 0; r < 4; ++r) {                        // float4 reads: 32B/lane/iter
        int e = r * 256 + tid, dd = e >> 5, i4 = e & 31;
        float4 v = *(const float4*)(src + (size_t)dd * HWSZ + i4 * 4);
        *(float4*)&xt[dd * 128 + i4 * 4] = v;
        xs += v.x * v.x + v.y * v.y + v.z * v.z + v.w * v.w;
    }
#pragma unroll
    for (int o = 32; o; o >>= 1) xs += __shfl_down(xs, o, 64);
    if ((tid & 63) == 0) xps[tid >> 6] = xs;
    __syncthreads();
    if (tid == 0) xxpart[cbid] = xps[0] + xps[1] + xps[2] + xps[3];
#pragma unroll
    for (int hl = 0; hl < 2; ++hl) {
        int g = hl * 256 + tid;
        int row = g >> 2, o = g & 3;
        unsigned short hi[8], lo[8];
#pragma unroll
        for (int j = 0; j < 8; ++j)
            bf16split(xt[(o * 8 + j) * 128 + row], hi[j], lo[j]);
        size_t fo = rhalf * 4096 + (size_t)(row >> 4) * 512 + (size_t)((row & 15) + 16 * o) * 8;
        size_t bh = (size_t)mt * 131072 + (size_t)dc       * 8192 + fo;
        size_t bl = (size_t)mt * 131072 + (size_t)(dc + 8) * 8192 + fo;
        *(s16x8*)(Xs + bh) = *(const s16x8*)hi;
        *(s16x8*)(Xs + bl) = *(const s16x8*)lo;
    }
}

// ------------------- gemm_argmin: 4-waves/SIMD B-direct MFMA + argmin
// 2048 blocks (512 mbi x 4 nt) x 512 threads (8 waves 2Mx4N; wave tile 64x64).
// 24 k-steps of BK=32. XCD swizzle keeps the 4 nt of each mbi on one XCD.
__global__ __launch_bounds__(512, 4) void gemm_argmin(
        const unsigned short* __restrict__ Xs, const unsigned short* __restrict__ Ws,
        const float* __restrict__ ww, unsigned long long* __restrict__ pbest) {
    __shared__ unsigned short lds[24576];                // 48 KB = 6 bufs x 4096 shorts
    const int tid = threadIdx.x, lane = tid & 63, w = tid >> 6;
    const int wm = w >> 2, wn = w & 3;
    const int col = lane & 15, q = lane >> 4;
    const int bid = blockIdx.x;
    const int xcd = bid & 7, slot = bid >> 3;
    const int nt = slot & 3, mbi = (slot >> 2) * 8 + xcd;         // 0..511
    const int mt = mbi >> 1, rh = mbi & 1;

    const unsigned short* XsB = Xs + (size_t)mt * 131072 + rh * 4096;
    const unsigned short* Bw  = Ws + (size_t)nt * 131072
                              + (wn >> 1) * 4096 + (wn & 1) * 2048 + lane * 8;

    f32x4 acc[4][4] = {};
    s16x8 B0[4], B1[4];
    const int aoff = wm * 2048 + lane * 8;               // wm*4 subtiles of 512

    auto SA = [&](int g, int p) {                        // stage A(g): 8 KB, 1 op/thread
        const int kA = (g & 7) | ((g >> 4) << 3);        // xhi,xhi,xlo
        __builtin_amdgcn_global_load_lds(
            (const AS1 unsigned*)(XsB + kA * 8192 + tid * 8),
            (AS3 unsigned*)&lds[p * 4096 + (tid >> 6) * 512 + (tid & 63) * 8], 16, 0, 0);
    };
    auto LB = [&](int g, s16x8* B) {                     // B(g) global->regs: 4 dwordx4
        const int kW = (g & 7) | (((g >> 3) & 1) << 3);  // whi,wlo,whi
        const s16x8* src = (const s16x8*)(Bw + kW * 8192);
        B[0] = src[0]; B[1] = src[64]; B[2] = src[128]; B[3] = src[192];
    };
#define BAR do { __builtin_amdgcn_s_barrier(); __builtin_amdgcn_sched_barrier(0); } while (0)

    // step: 4 A ds_reads | LB(g+1)->Bn | SA(g+4) | 16 MFMA | [gate+bar if odd]
    auto TILE = [&](int g, int p, int pstg, const s16x8* Bc, s16x8* Bn, bool sync) {
        s16x8 a[4];
#pragma unroll
        for (int mf = 0; mf < 4; ++mf)
            a[mf] = *(const s16x8*)&lds[p * 4096 + aoff + mf * 512];
        if (g + 1 < 24) LB(g + 1, Bn);
        if (g + 4 < 24) SA(g + 4, pstg);
#pragma unroll
        for (int mf = 0; mf < 4; ++mf) {
            acc[mf][0] = __builtin_amdgcn_mfma_f32_16x16x32_bf16(a[mf], Bc[0], acc[mf][0], 0, 0, 0);
            acc[mf][1] = __builtin_amdgcn_mfma_f32_16x16x32_bf16(a[mf], Bc[1], acc[mf][1], 0, 0, 0);
            acc[mf][2] = __builtin_amdgcn_mfma_f32_16x16x32_bf16(a[mf], Bc[2], acc[mf][2], 0, 0, 0);
            acc[mf][3] = __builtin_amdgcn_mfma_f32_16x16x32_bf16(a[mf], Bc[3], acc[mf][3], 0, 0, 0);
        }
        if (sync) {
            asm volatile("s_waitcnt vmcnt(5)" ::: "memory");
            BAR;
        }
    };

    // prologue: stage A(0..3) -> bufs 0..3; B(0) -> regs; drain stages; barrier
    SA(0, 0); SA(1, 1); SA(2, 2); SA(3, 3);
    LB(0, B0);
    asm volatile("s_waitcnt vmcnt(4)" ::: "memory");
    BAR;

#pragma unroll
    for (int t6 = 0; t6 < 3; ++t6) {                     // t = 0..17, fully unrolled
        TILE(t6 * 6 + 0, 0, 4, B0, B1, false);
        TILE(t6 * 6 + 1, 1, 5, B1, B0, true);
        TILE(t6 * 6 + 2, 2, 0, B0, B1, false);
        TILE(t6 * 6 + 3, 3, 1, B1, B0, true);
        TILE(t6 * 6 + 4, 4, 2, B0, B1, false);
        TILE(t6 * 6 + 5, 5, 3, B1, B0, true);
    }
    TILE(18, 0, 4, B0, B1, false);
    TILE(19, 1, 5, B1, B0, true);
    TILE(20, 2, 0, B0, B1, false);
    TILE(21, 3, 1, B1, B0, true);
    TILE(22, 4, 2, B0, B1, false);
    TILE(23, 5, 3, B1, B0, false);

    // ---- epilogue: per-row argmin; 2-step butterfly + [128][17] LDS fold
    __syncthreads();
    unsigned long long* kbuf = (unsigned long long*)lds;  // [128][17] u64 = 17.4 KB
    float wv[4];
#pragma unroll
    for (int nf = 0; nf < 4; ++nf) wv[nf] = ww[nt * 256 + wn * 64 + nf * 16 + col];
#pragma unroll
    for (int mf = 0; mf < 4; ++mf)
#pragma unroll
        for (int r = 0; r < 4; ++r) {
            unsigned long long key = ~0ull;
#pragma unroll
            for (int nf = 0; nf < 4; ++nf) {
                int kg = nt * 256 + wn * 64 + nf * 16 + col;
                float sd = wv[nf] - 2.f * acc[mf][nf][r];
                unsigned u = __float_as_uint(sd);
                u = (u & 0x80000000u) ? ~u : (u | 0x80000000u);
                unsigned long long kk = ((unsigned long long)u << 32) | (unsigned)kg;
                key = kk < key ? kk : key;
            }
#pragma unroll
            for (int off = 1; off < 4; off <<= 1) {
                unsigned klo = __shfl_xor((unsigned)key, off, 64);
                unsigned khi = __shfl_xor((unsigned)(key >> 32), off, 64);
                unsigned long long ok = ((unsigned long long)khi << 32) | klo;
                key = ok < key ? ok : key;
            }
            if ((col & 3) == 0)
                kbuf[(wm * 64 + mf * 16 + q * 4 + r) * 17 + wn * 4 + (col >> 2)] = key;
        }
    __syncthreads();
    if (tid < 128) {
        const unsigned long long* rowp = kbuf + tid * 17;
        unsigned long long km = rowp[0];
#pragma unroll
        for (int i = 1; i < 16; ++i) {
            unsigned long long k = rowp[i];
            km = k < km ? k : km;
        }
        pbest[(size_t)nt * 65536 + mbi * 128 + tid] = km;
    }
#undef BAR
}

// ---------- gather: cross-block argmin + idx + z_out + sum(best) + counts
__global__ __launch_bounds__(256) void gather_kernel(
        const float* __restrict__ cb, const unsigned long long* __restrict__ pbest,
        float* __restrict__ idx_out, unsigned int* __restrict__ counts,
        float* __restrict__ zout, float* __restrict__ partials) {
    const int tid = threadIdx.x;
    const int n   = blockIdx.x * 256 + tid;
    unsigned long long km = pbest[n];
#pragma unroll
    for (int nt = 1; nt < 4; ++nt) {
        unsigned long long k = pbest[(size_t)nt * 65536 + n];
        km = k < km ? k : km;
    }
    const int r = (int)(km & 0xFFFFFFFFu);
    idx_out[n] = (float)r;
    atomicAdd(&counts[r], 1u);

    // decode best = ww[r] - 2 x.w_r  (monotonic-u32 inverse)
    unsigned m = (unsigned)(km >> 32);
    m = (m & 0x80000000u) ? (m & 0x7FFFFFFFu) : ~m;
    float sd = __uint_as_float(m);

    const int b = n >> 12, hw = n & 4095;
    const float4* row4 = (const float4*)(cb + (size_t)r * DDIM);
    float* zp = zout + (size_t)b * CHW + hw;
#pragma unroll 8
    for (int c4 = 0; c4 < 64; ++c4) {
        float4 v = row4[c4];
        zp[(size_t)(c4 * 4 + 0) * HWSZ] = v.x;
        zp[(size_t)(c4 * 4 + 1) * HWSZ] = v.y;
        zp[(size_t)(c4 * 4 + 2) * HWSZ] = v.z;
        zp[(size_t)(c4 * 4 + 3) * HWSZ] = v.w;
    }
#pragma unroll
    for (int o = 32; o; o >>= 1) sd += __shfl_down(sd, o, 64);
    __shared__ float ps[4];
    if ((tid & 63) == 0) ps[tid >> 6] = sd;
    __syncthreads();
    if (tid == 0) partials[blockIdx.x] = ps[0] + ps[1] + ps[2] + ps[3];
}

// ------------------------------------------------------- loss + perplexity
__global__ __launch_bounds__(256) void final_kernel(
        const float* __restrict__ partials, const float* __restrict__ xxpart,
        const unsigned int* __restrict__ counts,
        float* __restrict__ out_loss, float* __restrict__ out_perp) {
    const int tid = threadIdx.x;
    float s = partials[tid];                             // sum(best) partials
#pragma unroll
    for (int i = 0; i < 16; ++i) s += xxpart[tid * 16 + i];  // + sum(x^2)
    float e = 0.f;
#pragma unroll
    for (int qq = 0; qq < 4; ++qq) {
        float p = (float)counts[tid * 4 + qq] * (1.f / 65536.f);
        e += p * logf(p + 1e-10f);
    }
#pragma unroll
    for (int o = 32; o; o >>= 1) {
        s += __shfl_down(s, o, 64);
        e += __shfl_down(e, o, 64);
    }
    __shared__ float ss[4], es[4];
    if ((tid & 63) == 0) { ss[tid >> 6] = s; es[tid >> 6] = e; }
    __syncthreads();
    if (tid == 0) {
        float S = ss[0] + ss[1] + ss[2] + ss[3];
        float E = es[0] + es[1] + es[2] + es[3];
        *out_loss = 0.25f * (S / (float)ZELEMS);
        *out_perp = expf(-E);
    }
}

extern "C" void kernel_launch(void* const* d_in, const int* in_sizes, int n_in,
                              void* d_out, int out_size, void* d_ws, size_t ws_size,
                              hipStream_t stream) {
    (void)in_sizes; (void)n_in; (void)out_size; (void)ws_size;
    const float* in = (const float*)d_in[0];
    const float* cb = (const float*)d_in[1];
    float* out  = (float*)d_out;
    float* zout = out;
    float* loss = out + ZELEMS;
    float* perp = out + ZELEMS + 1;
    float* idxf = out + ZELEMS + 2;

    unsigned int*       counts   = (unsigned int*)d_ws;
    float*              ww       = (float*)((char*)d_ws + 4096);
    float*              partials = (float*)((char*)d_ws + 8192);
    unsigned short*     Ws       = (unsigned short*)((char*)d_ws + 16384);
    unsigned long long* pbest    = (unsigned long long*)((char*)d_ws + 1064960);
    float*              xxpart   = (float*)((char*)d_ws + 3162112);
    unsigned short*     Xs       = (unsigned short*)zout;  // scratch; overwritten later

    prep_kernel <<<4128, 256, 0, stream>>>(cb, in, Ws, ww, Xs, xxpart, counts);
    gemm_argmin <<<2048, 512, 0, stream>>>(Xs, Ws, ww, pbest);
    gather_kernel<<<256, 256, 0, stream>>>(cb, pbest, idxf, counts, zout, partials);
    final_kernel <<<1,   256, 0, stream>>>(partials, xxpart, counts, loss, perp);
}

// Round 18
// 168.799 us; speedup vs baseline: 9.0869x; 1.0040x over previous
//
#include <hip/hip_runtime.h>
#include <math.h>

// VQ-VAE forward. inputs [16,256,64,64] f32 NCHW, codebook [1024,256] f32.
// N = 65536 points, D = 256, K = 1024.
// d_out f32: z_out [16,256,64,64] | loss | perplexity | idx [65536,1]
#define NPTS   65536
#define DDIM   256
#define KCODES 1024
#define HWSZ   4096
#define ZELEMS 16777216
#define CHW    1048576

// bf16-split GEMM, 3-product contraction 768 = [xhi|xhi|xlo].[whi|wlo|whi].
// R15 gemm kept verbatim (measured best: ~101.5 us, 4 waves/SIMD ceiling).
// R17: conv_x rewritten LDS-free -- lane l owns fragment slot l, so input
// reads are direct-global (each 16-lane group = one full 64B segment) and
// Xs fragment stores are contiguous 1KB/wave. Kills the 4-way xt bank
// conflict and the 256B-stride scattered stores of R16. Xs bytes identical.
// Loss trick: ||zq-x||^2 = best + ||x||^2 -> no x re-read in gather.
// X layout: [mt 256][chunk 16][rh 2][ms 8][lane 64][8] bf16 (64 MiB, z_out scratch)
// W layout: [ct 4][chunk 16][ch 2][ms 8][lane 64][8] bf16 (1 MiB, ws)
// ws: counts u32[1K]@0 | ww f32[1K]@4096 | partials f32[256]@8192 | Ws@16384
//     | pbest u64[4][64K]@1064960 | xxpart f32[4096]@3162112

typedef __attribute__((ext_vector_type(8))) short s16x8;
typedef __attribute__((ext_vector_type(4))) float f32x4;

#define AS1 __attribute__((address_space(1)))
#define AS3 __attribute__((address_space(3)))

__device__ __forceinline__ void bf16split(float x, unsigned short& h, unsigned short& l) {
    unsigned u  = __float_as_uint(x);
    unsigned hu = (u + 0x8000u) & 0xFFFF0000u;
    h = (unsigned short)(hu >> 16);
    float r = x - __uint_as_float(hu);
    l = (unsigned short)((__float_as_uint(r) + 0x8000u) >> 16);
}

// -------- prep: blocks 0..31 conv_w (+ counts zero), blocks 32..4127 conv_x
__global__ __launch_bounds__(256) void prep_kernel(
        const float* __restrict__ cb, const float* __restrict__ in,
        unsigned short* __restrict__ Ws, float* __restrict__ ww,
        unsigned short* __restrict__ Xs, float* __restrict__ xxpart,
        unsigned int* __restrict__ counts) {
    const int tid = threadIdx.x;
    if (blockIdx.x < 32) {
        // ---- conv_w path + zero counts
        int gid = blockIdx.x * 256 + tid;                // 0..8191
        if (gid < 1024) counts[gid] = 0u;
        int code = gid >> 3, o32 = gid & 7;
        int ct = code >> 8, r256 = code & 255, rh = r256 >> 7, rr = r256 & 127;
        unsigned short hi[32], lo[32];
        float ss = 0.f;
#pragma unroll
        for (int j4 = 0; j4 < 8; ++j4) {
            float4 v = *(const float4*)(cb + (size_t)code * DDIM + o32 * 32 + j4 * 4);
            ss += v.x * v.x + v.y * v.y + v.z * v.z + v.w * v.w;
            bf16split(v.x, hi[j4*4+0], lo[j4*4+0]);
            bf16split(v.y, hi[j4*4+1], lo[j4*4+1]);
            bf16split(v.z, hi[j4*4+2], lo[j4*4+2]);
            bf16split(v.w, hi[j4*4+3], lo[j4*4+3]);
        }
        ss += __shfl_down(ss, 4, 8);
        ss += __shfl_down(ss, 2, 8);
        ss += __shfl_down(ss, 1, 8);
        if (o32 == 0) ww[code] = ss;
        size_t bh = (size_t)ct * 131072 + (size_t)o32       * 8192 + rh * 4096 + (rr >> 4) * 512;
        size_t bl = (size_t)ct * 131072 + (size_t)(o32 + 8) * 8192 + rh * 4096 + (rr >> 4) * 512;
#pragma unroll
        for (int oct = 0; oct < 4; ++oct) {
            size_t fo = (size_t)((rr & 15) + 16 * oct) * 8;
            *(s16x8*)(Ws + bh + fo) = *(const s16x8*)&hi[oct * 8];
            *(s16x8*)(Ws + bl + fo) = *(const s16x8*)&lo[oct * 8];
        }
        return;
    }
    // ---- conv_x path (LDS-free): NCHW f32 -> fragment-ordered bf16 + sum(x^2)
    // lane l owns fragment slot l: row = (hl*4+w)*16 + (l&15), o = l>>4.
    // Global reads: 16-lane groups cover full 64B segments (coalesced).
    // Xs stores: base + l*16B -> contiguous 1KB per wave.
    __shared__ float xps[4];
    const int cbid = blockIdx.x - 32;                    // 0..4095
    const int rg = cbid >> 3, dc = cbid & 7;
    const int mt = rg >> 1, rhalf = rg & 1;
    const int b = (rg * 128) >> 12, hw0 = (rg * 128) & 4095;
    const int l = tid & 63, w = tid >> 6;
    const int o = l >> 4;
    const float* src = in + (size_t)b * CHW + (size_t)(dc * 32 + o * 8) * HWSZ + hw0;
    float xs = 0.f;
#pragma unroll
    for (int hl = 0; hl < 2; ++hl) {
        const int row = (hl * 4 + w) * 16 + (l & 15);
        unsigned short hi[8], lo[8];
#pragma unroll
        for (int j = 0; j < 8; ++j) {
            float v = src[(size_t)j * HWSZ + row];
            xs += v * v;
            bf16split(v, hi[j], lo[j]);
        }
        size_t fo = (size_t)rhalf * 4096 + (size_t)(hl * 4 + w) * 512 + (size_t)l * 8;
        size_t bh = (size_t)mt * 131072 + (size_t)dc * 8192 + fo;
        *(s16x8*)(Xs + bh)         = *(const s16x8*)hi;   // chunk dc   (hi)
        *(s16x8*)(Xs + bh + 65536) = *(const s16x8*)lo;   // chunk dc+8 (lo)
    }
#pragma unroll
    for (int oo = 32; oo; oo >>= 1) xs += __shfl_down(xs, oo, 64);
    if (l == 0) xps[w] = xs;
    __syncthreads();
    if (tid == 0) xxpart[cbid] = xps[0] + xps[1] + xps[2] + xps[3];
}

// ------------------- gemm_argmin: 4-waves/SIMD B-direct MFMA + argmin
// 2048 blocks (512 mbi x 4 nt) x 512 threads (8 waves 2Mx4N; wave tile 64x64).
// 24 k-steps of BK=32. XCD swizzle keeps the 4 nt of each mbi on one XCD.
__global__ __launch_bounds__(512, 4) void gemm_argmin(
        const unsigned short* __restrict__ Xs, const unsigned short* __restrict__ Ws,
        const float* __restrict__ ww, unsigned long long* __restrict__ pbest) {
    __shared__ unsigned short lds[24576];                // 48 KB = 6 bufs x 4096 shorts
    const int tid = threadIdx.x, lane = tid & 63, w = tid >> 6;
    const int wm = w >> 2, wn = w & 3;
    const int col = lane & 15, q = lane >> 4;
    const int bid = blockIdx.x;
    const int xcd = bid & 7, slot = bid >> 3;
    const int nt = slot & 3, mbi = (slot >> 2) * 8 + xcd;         // 0..511
    const int mt = mbi >> 1, rh = mbi & 1;

    const unsigned short* XsB = Xs + (size_t)mt * 131072 + rh * 4096;
    const unsigned short* Bw  = Ws + (size_t)nt * 131072
                              + (wn >> 1) * 4096 + (wn & 1) * 2048 + lane * 8;

    f32x4 acc[4][4] = {};
    s16x8 B0[4], B1[4];
    const int aoff = wm * 2048 + lane * 8;               // wm*4 subtiles of 512

    auto SA = [&](int g, int p) {                        // stage A(g): 8 KB, 1 op/thread
        const int kA = (g & 7) | ((g >> 4) << 3);        // xhi,xhi,xlo
        __builtin_amdgcn_global_load_lds(
            (const AS1 unsigned*)(XsB + kA * 8192 + tid * 8),
            (AS3 unsigned*)&lds[p * 4096 + (tid >> 6) * 512 + (tid & 63) * 8], 16, 0, 0);
    };
    auto LB = [&](int g, s16x8* B) {                     // B(g) global->regs: 4 dwordx4
        const int kW = (g & 7) | (((g >> 3) & 1) << 3);  // whi,wlo,whi
        const s16x8* src = (const s16x8*)(Bw + kW * 8192);
        B[0] = src[0]; B[1] = src[64]; B[2] = src[128]; B[3] = src[192];
    };
#define BAR do { __builtin_amdgcn_s_barrier(); __builtin_amdgcn_sched_barrier(0); } while (0)

    // step: 4 A ds_reads | LB(g+1)->Bn | SA(g+4) | 16 MFMA | [gate+bar if odd]
    auto TILE = [&](int g, int p, int pstg, const s16x8* Bc, s16x8* Bn, bool sync) {
        s16x8 a[4];
#pragma unroll
        for (int mf = 0; mf < 4; ++mf)
            a[mf] = *(const s16x8*)&lds[p * 4096 + aoff + mf * 512];
        if (g + 1 < 24) LB(g + 1, Bn);
        if (g + 4 < 24) SA(g + 4, pstg);
#pragma unroll
        for (int mf = 0; mf < 4; ++mf) {
            acc[mf][0] = __builtin_amdgcn_mfma_f32_16x16x32_bf16(a[mf], Bc[0], acc[mf][0], 0, 0, 0);
            acc[mf][1] = __builtin_amdgcn_mfma_f32_16x16x32_bf16(a[mf], Bc[1], acc[mf][1], 0, 0, 0);
            acc[mf][2] = __builtin_amdgcn_mfma_f32_16x16x32_bf16(a[mf], Bc[2], acc[mf][2], 0, 0, 0);
            acc[mf][3] = __builtin_amdgcn_mfma_f32_16x16x32_bf16(a[mf], Bc[3], acc[mf][3], 0, 0, 0);
        }
        if (sync) {
            asm volatile("s_waitcnt vmcnt(5)" ::: "memory");
            BAR;
        }
    };

    // prologue: stage A(0..3) -> bufs 0..3; B(0) -> regs; drain stages; barrier
    SA(0, 0); SA(1, 1); SA(2, 2); SA(3, 3);
    LB(0, B0);
    asm volatile("s_waitcnt vmcnt(4)" ::: "memory");
    BAR;

#pragma unroll
    for (int t6 = 0; t6 < 3; ++t6) {                     // t = 0..17, fully unrolled
        TILE(t6 * 6 + 0, 0, 4, B0, B1, false);
        TILE(t6 * 6 + 1, 1, 5, B1, B0, true);
        TILE(t6 * 6 + 2, 2, 0, B0, B1, false);
        TILE(t6 * 6 + 3, 3, 1, B1, B0, true);
        TILE(t6 * 6 + 4, 4, 2, B0, B1, false);
        TILE(t6 * 6 + 5, 5, 3, B1, B0, true);
    }
    TILE(18, 0, 4, B0, B1, false);
    TILE(19, 1, 5, B1, B0, true);
    TILE(20, 2, 0, B0, B1, false);
    TILE(21, 3, 1, B1, B0, true);
    TILE(22, 4, 2, B0, B1, false);
    TILE(23, 5, 3, B1, B0, false);

    // ---- epilogue: per-row argmin; 2-step butterfly + [128][17] LDS fold
    __syncthreads();
    unsigned long long* kbuf = (unsigned long long*)lds;  // [128][17] u64 = 17.4 KB
    float wv[4];
#pragma unroll
    for (int nf = 0; nf < 4; ++nf) wv[nf] = ww[nt * 256 + wn * 64 + nf * 16 + col];
#pragma unroll
    for (int mf = 0; mf < 4; ++mf)
#pragma unroll
        for (int r = 0; r < 4; ++r) {
            unsigned long long key = ~0ull;
#pragma unroll
            for (int nf = 0; nf < 4; ++nf) {
                int kg = nt * 256 + wn * 64 + nf * 16 + col;
                float sd = wv[nf] - 2.f * acc[mf][nf][r];
                unsigned u = __float_as_uint(sd);
                u = (u & 0x80000000u) ? ~u : (u | 0x80000000u);
                unsigned long long kk = ((unsigned long long)u << 32) | (unsigned)kg;
                key = kk < key ? kk : key;
            }
#pragma unroll
            for (int off = 1; off < 4; off <<= 1) {
                unsigned klo = __shfl_xor((unsigned)key, off, 64);
                unsigned khi = __shfl_xor((unsigned)(key >> 32), off, 64);
                unsigned long long ok = ((unsigned long long)khi << 32) | klo;
                key = ok < key ? ok : key;
            }
            if ((col & 3) == 0)
                kbuf[(wm * 64 + mf * 16 + q * 4 + r) * 17 + wn * 4 + (col >> 2)] = key;
        }
    __syncthreads();
    if (tid < 128) {
        const unsigned long long* rowp = kbuf + tid * 17;
        unsigned long long km = rowp[0];
#pragma unroll
        for (int i = 1; i < 16; ++i) {
            unsigned long long k = rowp[i];
            km = k < km ? k : km;
        }
        pbest[(size_t)nt * 65536 + mbi * 128 + tid] = km;
    }
#undef BAR
}

// ---------- gather: cross-block argmin + idx + z_out + sum(best) + counts
__global__ __launch_bounds__(256) void gather_kernel(
        const float* __restrict__ cb, const unsigned long long* __restrict__ pbest,
        float* __restrict__ idx_out, unsigned int* __restrict__ counts,
        float* __restrict__ zout, float* __restrict__ partials) {
    const int tid = threadIdx.x;
    const int n   = blockIdx.x * 256 + tid;
    unsigned long long km = pbest[n];
#pragma unroll
    for (int nt = 1; nt < 4; ++nt) {
        unsigned long long k = pbest[(size_t)nt * 65536 + n];
        km = k < km ? k : km;
    }
    const int r = (int)(km & 0xFFFFFFFFu);
    idx_out[n] = (float)r;
    atomicAdd(&counts[r], 1u);

    // decode best = ww[r] - 2 x.w_r  (monotonic-u32 inverse)
    unsigned m = (unsigned)(km >> 32);
    m = (m & 0x80000000u) ? (m & 0x7FFFFFFFu) : ~m;
    float sd = __uint_as_float(m);

    const int b = n >> 12, hw = n & 4095;
    const float4* row4 = (const float4*)(cb + (size_t)r * DDIM);
    float* zp = zout + (size_t)b * CHW + hw;
#pragma unroll 8
    for (int c4 = 0; c4 < 64; ++c4) {
        float4 v = row4[c4];
        zp[(size_t)(c4 * 4 + 0) * HWSZ] = v.x;
        zp[(size_t)(c4 * 4 + 1) * HWSZ] = v.y;
        zp[(size_t)(c4 * 4 + 2) * HWSZ] = v.z;
        zp[(size_t)(c4 * 4 + 3) * HWSZ] = v.w;
    }
#pragma unroll
    for (int o = 32; o; o >>= 1) sd += __shfl_down(sd, o, 64);
    __shared__ float ps[4];
    if ((tid & 63) == 0) ps[tid >> 6] = sd;
    __syncthreads();
    if (tid == 0) partials[blockIdx.x] = ps[0] + ps[1] + ps[2] + ps[3];
}

// ------------------------------------------------------- loss + perplexity
__global__ __launch_bounds__(256) void final_kernel(
        const float* __restrict__ partials, const float* __restrict__ xxpart,
        const unsigned int* __restrict__ counts,
        float* __restrict__ out_loss, float* __restrict__ out_perp) {
    const int tid = threadIdx.x;
    float s = partials[tid];                             // sum(best) partials
#pragma unroll
    for (int i = 0; i < 16; ++i) s += xxpart[tid * 16 + i];  // + sum(x^2)
    float e = 0.f;
#pragma unroll
    for (int qq = 0; qq < 4; ++qq) {
        float p = (float)counts[tid * 4 + qq] * (1.f / 65536.f);
        e += p * logf(p + 1e-10f);
    }
#pragma unroll
    for (int o = 32; o; o >>= 1) {
        s += __shfl_down(s, o, 64);
        e += __shfl_down(e, o, 64);
    }
    __shared__ float ss[4], es[4];
    if ((tid & 63) == 0) { ss[tid >> 6] = s; es[tid >> 6] = e; }
    __syncthreads();
    if (tid == 0) {
        float S = ss[0] + ss[1] + ss[2] + ss[3];
        float E = es[0] + es[1] + es[2] + es[3];
        *out_loss = 0.25f * (S / (float)ZELEMS);
        *out_perp = expf(-E);
    }
}

extern "C" void kernel_launch(void* const* d_in, const int* in_sizes, int n_in,
                              void* d_out, int out_size, void* d_ws, size_t ws_size,
                              hipStream_t stream) {
    (void)in_sizes; (void)n_in; (void)out_size; (void)ws_size;
    const float* in = (const float*)d_in[0];
    const float* cb = (const float*)d_in[1];
    float* out  = (float*)d_out;
    float* zout = out;
    float* loss = out + ZELEMS;
    float* perp = out + ZELEMS + 1;
    float* idxf = out + ZELEMS + 2;

    unsigned int*       counts   = (unsigned int*)d_ws;
    float*              ww       = (float*)((char*)d_ws + 4096);
    float*              partials = (float*)((char*)d_ws + 8192);
    unsigned short*     Ws       = (unsigned short*)((char*)d_ws + 16384);
    unsigned long long* pbest    = (unsigned long long*)((char*)d_ws + 1064960);
    float*              xxpart   = (float*)((char*)d_ws + 3162112);
    unsigned short*     Xs       = (unsigned short*)zout;  // scratch; overwritten later

    prep_kernel <<<4128, 256, 0, stream>>>(cb, in, Ws, ww, Xs, xxpart, counts);
    gemm_argmin <<<2048, 512, 0, stream>>>(Xs, Ws, ww, pbest);
    gather_kernel<<<256, 256, 0, stream>>>(cb, pbest, idxf, counts, zout, partials);
    final_kernel <<<1,   256, 0, stream>>>(partials, xxpart, counts, loss, perp);
}